// Round 7
// baseline (302.438 us; speedup 1.0000x reference)
//
#include <hip/hip_runtime.h>

// Problem constants (from reference): x = (32, 256, 56, 56) fp32
#define M_BATCH 32
#define D_FEAT 256
#define HW 3136              // floats per channel
#define HW4 784              // float4 per channel
#define NGROUPS 16
#define GS 16
#define NTOT (M_BATCH * HW)  // 100352 samples per channel
#define TRI 136              // 16*17/2 packed lower triangle
#define EPS_W 1e-6f

// Quarter-tiling: block owns (b,g); per quarter, each of the 16 channels is
// fetched as ONE contiguous 3136B burst (consecutive threads -> consecutive
// float4) into a linear 50KB LDS tile. This clusters page/row accesses that
// in r0-r4 were 16 concurrent 12.5KB-stride streams (pinned at 2.2 B/cyc/CU).
#define NQ 4
#define QPOS4 196            // float4 per channel-quarter
#define QPOS2 392            // float2 positions per channel-quarter
#define TILE4 (GS * QPOS4)   // 3136 float4 = 50176 B per tile
#define NROUND 13            // ceil(TILE4/256); round 12 active on wave 0 only

__device__ __host__ constexpr int tidx(int i, int j) { return i * (i + 1) / 2 + j; }

// Barrier that drains ONLY lgkm (LDS) - outstanding global loads stay in
// flight across it (issue-early/write-late). sched_barrier per rule #18.
__device__ __forceinline__ void bar_lgkm() {
    asm volatile("s_waitcnt lgkmcnt(0)" ::: "memory");
    __builtin_amdgcn_s_barrier();
    __builtin_amdgcn_sched_barrier(0);
}

// ---------------------------------------------------------------------------
// Pass 1: per-channel sums + per-group packed Gram.
// Per quarter: [13 burst loads -> regs] [bar] [ds_write linear] [bar]
// [Gram from LDS, acc in regs]. One reduce+atomic epilogue per block.
// ---------------------------------------------------------------------------
__global__ __launch_bounds__(256, 2) void whiten_stats(const float4* __restrict__ x4,
                                                       float* __restrict__ sums,
                                                       float* __restrict__ gram) {
    __shared__ float4 tile4[TILE4];          // 50176 B
    __shared__ float red[4][TRI + GS];       // 2432 B
    const int tid = threadIdx.x, w = tid >> 6, lane = tid & 63;
    const int b = blockIdx.x, g = blockIdx.y;
    const float4* rbase4 = x4 + ((size_t)b * D_FEAT + (size_t)g * GS) * HW4;

    float acc[TRI], sv[GS];
#pragma unroll
    for (int k = 0; k < TRI; ++k) acc[k] = 0.0f;
#pragma unroll
    for (int j = 0; j < GS; ++j) sv[j] = 0.0f;

#pragma unroll 1
    for (int q = 0; q < NQ; ++q) {
        // P1a: issue clustered burst loads (13 in flight per thread)
        float4 st[NROUND];
#pragma unroll
        for (int r = 0; r < NROUND; ++r) {
            const int k = tid + r * 256;
            if (k < TILE4) {
                const int ch = k / QPOS4, pos = k - ch * QPOS4;
                st[r] = rbase4[(size_t)ch * HW4 + q * QPOS4 + pos];
            }
        }
        bar_lgkm();  // previous quarter's LDS reads complete block-wide
        // P1b: write-late (compiler inserts per-value vmcnt waits)
#pragma unroll
        for (int r = 0; r < NROUND; ++r) {
            const int k = tid + r * 256;
            if (k < TILE4) tile4[k] = st[r];
        }
        bar_lgkm();  // tile visible to all waves

        // P2: Gram accumulate from LDS (column p is thread-private)
        const float2* t2 = (const float2*)tile4;
#pragma unroll 1
        for (int p = tid; p < QPOS2; p += 256) {
            float2 v[GS];
#pragma unroll
            for (int j = 0; j < GS; ++j) v[j] = t2[j * QPOS2 + p];
#pragma unroll
            for (int i = 0; i < GS; ++i) {
                sv[i] += v[i].x + v[i].y;
#pragma unroll
                for (int j = 0; j <= i; ++j) {
                    float t = acc[tidx(i, j)];
                    t = fmaf(v[i].x, v[j].x, t);
                    t = fmaf(v[i].y, v[j].y, t);
                    acc[tidx(i, j)] = t;
                }
            }
        }
    }

    // Epilogue (identical to the round-4 passing kernel): wave shuffle-reduce
    // -> per-wave LDS slot -> 4-way sum -> one atomic per cell per block.
#pragma unroll
    for (int k = 0; k < TRI; ++k) {
        float r = acc[k];
#pragma unroll
        for (int off = 32; off > 0; off >>= 1) r += __shfl_down(r, off, 64);
        if (lane == 0) red[w][k] = r;
    }
#pragma unroll
    for (int j = 0; j < GS; ++j) {
        float r = sv[j];
#pragma unroll
        for (int off = 32; off > 0; off >>= 1) r += __shfl_down(r, off, 64);
        if (lane == 0) red[w][TRI + j] = r;
    }
    __syncthreads();
    if (tid < TRI) {
        atomicAdd(&gram[g * TRI + tid],
                  red[0][tid] + red[1][tid] + red[2][tid] + red[3][tid]);
    } else if (tid < TRI + GS) {
        atomicAdd(&sums[g * GS + (tid - TRI)],
                  red[0][tid] + red[1][tid] + red[2][tid] + red[3][tid]);
    }
}

// ---------------------------------------------------------------------------
// Pass 2: sigma -> Cholesky -> inv(T). Tiny, unchanged (proven).
// ---------------------------------------------------------------------------
__global__ __launch_bounds__(64, 1) void whiten_solve(const float* __restrict__ sums,
                                                      const float* __restrict__ gram,
                                                      float* __restrict__ wout,
                                                      float* __restrict__ muout) {
    const int g = threadIdx.x;
    if (g >= NGROUPS) return;

    float mu[GS];
#pragma unroll
    for (int j = 0; j < GS; ++j) mu[j] = sums[g * GS + j] * (1.0f / (float)NTOT);

    float S[TRI];
#pragma unroll
    for (int i = 0; i < GS; ++i) {
#pragma unroll
        for (int j = 0; j <= i; ++j) {
            float sg = (gram[g * TRI + tidx(i, j)] - (float)NTOT * mu[i] * mu[j])
                       * (1.0f / (float)(NTOT - 1));
            sg *= (1.0f - EPS_W);
            if (i == j) sg += EPS_W;
            S[tidx(i, j)] = sg;
        }
    }

#pragma unroll
    for (int c = 0; c < GS; ++c) {
        float d = S[tidx(c, c)];
#pragma unroll
        for (int k = 0; k < c; ++k) d -= S[tidx(c, k)] * S[tidx(c, k)];
        d = sqrtf(d);
        S[tidx(c, c)] = d;
        const float inv = 1.0f / d;
#pragma unroll
        for (int i = c + 1; i < GS; ++i) {
            float t = S[tidx(i, c)];
#pragma unroll
            for (int k = 0; k < c; ++k) t -= S[tidx(i, k)] * S[tidx(c, k)];
            S[tidx(i, c)] = t * inv;
        }
    }

#pragma unroll
    for (int c = 0; c < GS; ++c) {
        const float wcc = 1.0f / S[tidx(c, c)];
        S[tidx(c, c)] = wcc;
#pragma unroll
        for (int i = c + 1; i < GS; ++i) {
            float a = 0.0f;
#pragma unroll
            for (int k = c; k < i; ++k) a += S[tidx(i, k)] * S[tidx(k, c)];
            S[tidx(i, c)] = -a / S[tidx(i, i)];
        }
    }

#pragma unroll
    for (int k = 0; k < TRI; ++k) wout[g * TRI + k] = S[k];
#pragma unroll
    for (int j = 0; j < GS; ++j) muout[g * GS + j] = mu[j];
}

// ---------------------------------------------------------------------------
// Pass 3: out = W*(x-mu). Per quarter: [burst loads] [bar] [ds_write] [bar]
// [in-place matvec, column-private] [bar] [burst sweep-out stores].
// ---------------------------------------------------------------------------
__global__ __launch_bounds__(256, 2) void whiten_apply(const float4* __restrict__ x4,
                                                       const float* __restrict__ wmat,
                                                       const float* __restrict__ muv,
                                                       float4* __restrict__ out4) {
    __shared__ float4 tile4[TILE4];  // 50176 B
    const int tid = threadIdx.x;
    const int b = blockIdx.x, g = blockIdx.y;
    const size_t roff = ((size_t)b * D_FEAT + (size_t)g * GS) * HW4;
    const float4* rbase4 = x4 + roff;
    float4* obase4 = out4 + roff;

    float wv[TRI], cb[GS];
#pragma unroll
    for (int k = 0; k < TRI; ++k) wv[k] = wmat[g * TRI + k];
#pragma unroll
    for (int i = 0; i < GS; ++i) {
        float c = 0.0f;
#pragma unroll
        for (int j = 0; j <= i; ++j) c = fmaf(wv[tidx(i, j)], muv[g * GS + j], c);
        cb[i] = c;
    }

#pragma unroll 1
    for (int q = 0; q < NQ; ++q) {
        float4 st[NROUND];
#pragma unroll
        for (int r = 0; r < NROUND; ++r) {
            const int k = tid + r * 256;
            if (k < TILE4) {
                const int ch = k / QPOS4, pos = k - ch * QPOS4;
                st[r] = rbase4[(size_t)ch * HW4 + q * QPOS4 + pos];
            }
        }
        bar_lgkm();  // previous sweep-out's LDS reads done block-wide
#pragma unroll
        for (int r = 0; r < NROUND; ++r) {
            const int k = tid + r * 256;
            if (k < TILE4) tile4[k] = st[r];
        }
        bar_lgkm();  // x tile visible

        // In-place triangular matvec. Thread owns float2 column p exclusively:
        // reads 16 channels at p into regs, writes 16 outputs at p.
        {
            const float2* t2 = (const float2*)tile4;
            float2* t2w = (float2*)tile4;
#pragma unroll 1
            for (int p = tid; p < QPOS2; p += 256) {
                float2 v[GS];
#pragma unroll
                for (int j = 0; j < GS; ++j) v[j] = t2[j * QPOS2 + p];
#pragma unroll
                for (int i = 0; i < GS; ++i) {
                    float2 o;
                    o.x = -cb[i];
                    o.y = -cb[i];
#pragma unroll
                    for (int j = 0; j <= i; ++j) {
                        const float wc = wv[tidx(i, j)];
                        o.x = fmaf(wc, v[j].x, o.x);
                        o.y = fmaf(wc, v[j].y, o.y);
                    }
                    t2w[i * QPOS2 + p] = o;
                }
            }
        }
        bar_lgkm();  // all o-writes visible before cross-column sweep-out

        // Burst sweep-out: contiguous stores, same clustered mapping as loads
#pragma unroll
        for (int r = 0; r < NROUND; ++r) {
            const int k = tid + r * 256;
            if (k < TILE4) {
                const int ch = k / QPOS4, pos = k - ch * QPOS4;
                obase4[(size_t)ch * HW4 + q * QPOS4 + pos] = tile4[k];
            }
        }
    }
}

extern "C" void kernel_launch(void* const* d_in, const int* in_sizes, int n_in,
                              void* d_out, int out_size, void* d_ws, size_t ws_size,
                              hipStream_t stream) {
    const float* x = (const float*)d_in[0];
    float* out = (float*)d_out;

    float* ws = (float*)d_ws;
    float* sums = ws;                   // 256 floats
    float* gram = ws + 256;             // 2176 floats
    float* wmat = ws + 256 + 2176;      // 2176 floats
    float* muv  = wmat + 2176;          // 256 floats

    // accumulators must start at zero (ws is poisoned each call)
    hipMemsetAsync(ws, 0, (256 + 2176) * sizeof(float), stream);

    dim3 grid(M_BATCH, NGROUPS);
    whiten_stats<<<grid, 256, 0, stream>>>((const float4*)x, sums, gram);
    whiten_solve<<<1, 64, 0, stream>>>(sums, gram, wmat, muv);
    whiten_apply<<<grid, 256, 0, stream>>>((const float4*)x, wmat, muv, (float4*)out);
}

// Round 9
// 236.856 us; speedup vs baseline: 1.2769x; 1.2769x over previous
//
#include <hip/hip_runtime.h>

// Problem constants (from reference): x = (32, 256, 56, 56) fp32
#define M_BATCH 32
#define D_FEAT 256
#define HW 3136              // floats per channel
#define HW4 784              // float4 per channel
#define HW2 1568             // float2 per channel
#define NGROUPS 16
#define GS 16
#define NTOT (M_BATCH * HW)  // 100352 samples per channel
#define TRI 136              // 16*17/2 packed lower triangle
#define EPS_W 1e-6f

// Quarter tiling: block owns (b,g) = 16 channels x 12544B. Per quarter the
// 16 channel-quarters (196 float4 each, contiguous 3136B bursts) are DMA'd
// into a linear 50KB LDS tile by 49 FULL-WAVE global_load_lds calls
// (m97-verified shape: wave-uniform LDS base + lane*16, per-lane global addr).
// r7 proved clustered bursts sustain ~2.4 TB/s; r7's spills (52 staging regs
// + 136 acc) are gone: no staging regs, and Gram rows are wave-split (r2).
#define NQ 4
#define QPOS4 196            // float4 per channel-quarter
#define QPOS2 392            // float2 positions per channel-quarter
#define TILE4 (GS * QPOS4)   // 3136 float4 = 50176 B
#define NCALL 49             // full-wave 1KB DMA calls per quarter

__device__ __host__ constexpr int tidx(int i, int j) { return i * (i + 1) / 2 + j; }

__device__ __forceinline__ void async16(const float4* g, float4* l) {
    __builtin_amdgcn_global_load_lds(
        (const __attribute__((address_space(1))) void*)g,
        (__attribute__((address_space(3))) void*)l, 16, 0, 0);
}

__device__ __forceinline__ void wave_red_atomic(float v, int lane, float* addr) {
#pragma unroll
    for (int off = 32; off > 0; off >>= 1) v += __shfl_down(v, off, 64);
    if (lane == 0) atomicAdd(addr, v);
}

// ---------------------------------------------------------------------------
// Pass 1: per-channel sums + per-group packed Gram.
// Wave w (== R0) owns rows {w, 15-w, w+4, 11-w} = 34 cells, all in registers.
// Per quarter: [issue 12-13 full-wave DMAs] [vmcnt0+bar] [sweep all 392
// positions for own rows] [bar]. Epilogue: shuffle-reduce + direct atomics.
// ---------------------------------------------------------------------------
template <int R0, int R1, int R2, int R3>
__device__ __forceinline__ void stats_wave(const float4* __restrict__ rbase4,
                                           float* __restrict__ sums,
                                           float* __restrict__ gram,
                                           float4* tile4, int g, int lane) {
    // Per-lane global float4-offsets for this wave's DMA calls (q-invariant part)
    int off[13];
#pragma unroll
    for (int i = 0; i < 13; ++i) {
        const int c = R0 + 4 * i;            // compile-time per instantiation
        if (c < NCALL) {
            const int k = c * 64 + lane;     // linear tile element
            const int ch = k / QPOS4;
            off[i] = ch * HW4 + (k - ch * QPOS4);
        }
    }

    float a0[R0 + 1], a1[R1 + 1], a2[R2 + 1], a3[R3 + 1];
#pragma unroll
    for (int j = 0; j <= R0; ++j) a0[j] = 0.0f;
#pragma unroll
    for (int j = 0; j <= R1; ++j) a1[j] = 0.0f;
#pragma unroll
    for (int j = 0; j <= R2; ++j) a2[j] = 0.0f;
#pragma unroll
    for (int j = 0; j <= R3; ++j) a3[j] = 0.0f;
    float sv0 = 0.0f, sv1 = 0.0f, sv2 = 0.0f, sv3 = 0.0f;

#pragma unroll 1
    for (int q = 0; q < NQ; ++q) {
#pragma unroll
        for (int i = 0; i < 13; ++i) {
            const int c = R0 + 4 * i;
            if (c < NCALL)
                async16(rbase4 + off[i] + q * QPOS4, tile4 + c * 64);
        }
        asm volatile("s_waitcnt vmcnt(0)" ::: "memory");  // own DMAs landed
        __builtin_amdgcn_s_barrier();                     // tile complete
        __builtin_amdgcn_sched_barrier(0);

        const float2* t2 = (const float2*)tile4;
#pragma unroll 1
        for (int it = 0; it < 7; ++it) {
            const int p = lane + it * 64;
            if (p < QPOS2) {
                float2 v[GS];
#pragma unroll
                for (int j = 0; j < GS; ++j) v[j] = t2[j * QPOS2 + p];
                sv0 += v[R0].x + v[R0].y;
                sv1 += v[R1].x + v[R1].y;
                sv2 += v[R2].x + v[R2].y;
                sv3 += v[R3].x + v[R3].y;
#pragma unroll
                for (int j = 0; j <= R0; ++j) { float t = a0[j]; t = fmaf(v[R0].x, v[j].x, t); t = fmaf(v[R0].y, v[j].y, t); a0[j] = t; }
#pragma unroll
                for (int j = 0; j <= R1; ++j) { float t = a1[j]; t = fmaf(v[R1].x, v[j].x, t); t = fmaf(v[R1].y, v[j].y, t); a1[j] = t; }
#pragma unroll
                for (int j = 0; j <= R2; ++j) { float t = a2[j]; t = fmaf(v[R2].x, v[j].x, t); t = fmaf(v[R2].y, v[j].y, t); a2[j] = t; }
#pragma unroll
                for (int j = 0; j <= R3; ++j) { float t = a3[j]; t = fmaf(v[R3].x, v[j].x, t); t = fmaf(v[R3].y, v[j].y, t); a3[j] = t; }
            }
        }
        __builtin_amdgcn_s_barrier();  // all waves done reading tile
        __builtin_amdgcn_sched_barrier(0);
    }

    wave_red_atomic(sv0, lane, &sums[g * GS + R0]);
    wave_red_atomic(sv1, lane, &sums[g * GS + R1]);
    wave_red_atomic(sv2, lane, &sums[g * GS + R2]);
    wave_red_atomic(sv3, lane, &sums[g * GS + R3]);
#pragma unroll
    for (int j = 0; j <= R0; ++j) wave_red_atomic(a0[j], lane, &gram[g * TRI + tidx(R0, j)]);
#pragma unroll
    for (int j = 0; j <= R1; ++j) wave_red_atomic(a1[j], lane, &gram[g * TRI + tidx(R1, j)]);
#pragma unroll
    for (int j = 0; j <= R2; ++j) wave_red_atomic(a2[j], lane, &gram[g * TRI + tidx(R2, j)]);
#pragma unroll
    for (int j = 0; j <= R3; ++j) wave_red_atomic(a3[j], lane, &gram[g * TRI + tidx(R3, j)]);
}

__global__ __launch_bounds__(256, 2) void whiten_stats(const float4* __restrict__ x4,
                                                       float* __restrict__ sums,
                                                       float* __restrict__ gram) {
    __shared__ float4 tile4[TILE4];  // 50176 B
    const int tid = threadIdx.x, w = tid >> 6, lane = tid & 63;
    const int g = blockIdx.y;
    const float4* rbase4 = x4 + ((size_t)blockIdx.x * D_FEAT + (size_t)g * GS) * HW4;
    switch (w) {
        case 0: stats_wave<0, 15, 4, 11>(rbase4, sums, gram, tile4, g, lane); break;
        case 1: stats_wave<1, 14, 5, 10>(rbase4, sums, gram, tile4, g, lane); break;
        case 2: stats_wave<2, 13, 6, 9>(rbase4, sums, gram, tile4, g, lane); break;
        default: stats_wave<3, 12, 7, 8>(rbase4, sums, gram, tile4, g, lane); break;
    }
}

// ---------------------------------------------------------------------------
// Pass 2: sigma -> Cholesky -> inv(T). Tiny, unchanged (proven).
// ---------------------------------------------------------------------------
__global__ __launch_bounds__(64, 1) void whiten_solve(const float* __restrict__ sums,
                                                      const float* __restrict__ gram,
                                                      float* __restrict__ wout,
                                                      float* __restrict__ muout) {
    const int g = threadIdx.x;
    if (g >= NGROUPS) return;

    float mu[GS];
#pragma unroll
    for (int j = 0; j < GS; ++j) mu[j] = sums[g * GS + j] * (1.0f / (float)NTOT);

    float S[TRI];
#pragma unroll
    for (int i = 0; i < GS; ++i) {
#pragma unroll
        for (int j = 0; j <= i; ++j) {
            float sg = (gram[g * TRI + tidx(i, j)] - (float)NTOT * mu[i] * mu[j])
                       * (1.0f / (float)(NTOT - 1));
            sg *= (1.0f - EPS_W);
            if (i == j) sg += EPS_W;
            S[tidx(i, j)] = sg;
        }
    }

#pragma unroll
    for (int c = 0; c < GS; ++c) {
        float d = S[tidx(c, c)];
#pragma unroll
        for (int k = 0; k < c; ++k) d -= S[tidx(c, k)] * S[tidx(c, k)];
        d = sqrtf(d);
        S[tidx(c, c)] = d;
        const float inv = 1.0f / d;
#pragma unroll
        for (int i = c + 1; i < GS; ++i) {
            float t = S[tidx(i, c)];
#pragma unroll
            for (int k = 0; k < c; ++k) t -= S[tidx(i, k)] * S[tidx(c, k)];
            S[tidx(i, c)] = t * inv;
        }
    }

#pragma unroll
    for (int c = 0; c < GS; ++c) {
        const float wcc = 1.0f / S[tidx(c, c)];
        S[tidx(c, c)] = wcc;
#pragma unroll
        for (int i = c + 1; i < GS; ++i) {
            float a = 0.0f;
#pragma unroll
            for (int k = c; k < i; ++k) a += S[tidx(i, k)] * S[tidx(k, c)];
            S[tidx(i, c)] = -a / S[tidx(i, i)];
        }
    }

#pragma unroll
    for (int k = 0; k < TRI; ++k) wout[g * TRI + k] = S[k];
#pragma unroll
    for (int j = 0; j < GS; ++j) muout[g * GS + j] = mu[j];
}

// ---------------------------------------------------------------------------
// Pass 3: out = W*(x-mu). Same DMA staging; wave w owns OUTPUT rows
// {w,15-w,w+4,11-w} (34 coeffs in regs, mean folded into per-row constant)
// and stores them directly to global (coalesced float2 per row burst).
// ---------------------------------------------------------------------------
template <int R0, int R1, int R2, int R3>
__device__ __forceinline__ void apply_wave(const float4* __restrict__ rbase4,
                                           float2* __restrict__ obase2,
                                           const float* __restrict__ wmat,
                                           const float* __restrict__ muv,
                                           float4* tile4, int g, int lane) {
    float w0[R0 + 1], w1[R1 + 1], w2[R2 + 1], w3[R3 + 1];
    float cb0 = 0.0f, cb1 = 0.0f, cb2 = 0.0f, cb3 = 0.0f;
#pragma unroll
    for (int j = 0; j <= R0; ++j) { w0[j] = wmat[g * TRI + tidx(R0, j)]; cb0 = fmaf(w0[j], muv[g * GS + j], cb0); }
#pragma unroll
    for (int j = 0; j <= R1; ++j) { w1[j] = wmat[g * TRI + tidx(R1, j)]; cb1 = fmaf(w1[j], muv[g * GS + j], cb1); }
#pragma unroll
    for (int j = 0; j <= R2; ++j) { w2[j] = wmat[g * TRI + tidx(R2, j)]; cb2 = fmaf(w2[j], muv[g * GS + j], cb2); }
#pragma unroll
    for (int j = 0; j <= R3; ++j) { w3[j] = wmat[g * TRI + tidx(R3, j)]; cb3 = fmaf(w3[j], muv[g * GS + j], cb3); }

    int off[13];
#pragma unroll
    for (int i = 0; i < 13; ++i) {
        const int c = R0 + 4 * i;
        if (c < NCALL) {
            const int k = c * 64 + lane;
            const int ch = k / QPOS4;
            off[i] = ch * HW4 + (k - ch * QPOS4);
        }
    }

#pragma unroll 1
    for (int q = 0; q < NQ; ++q) {
#pragma unroll
        for (int i = 0; i < 13; ++i) {
            const int c = R0 + 4 * i;
            if (c < NCALL)
                async16(rbase4 + off[i] + q * QPOS4, tile4 + c * 64);
        }
        asm volatile("s_waitcnt vmcnt(0)" ::: "memory");
        __builtin_amdgcn_s_barrier();
        __builtin_amdgcn_sched_barrier(0);

        const float2* t2 = (const float2*)tile4;
#pragma unroll 1
        for (int it = 0; it < 7; ++it) {
            const int p = lane + it * 64;
            if (p < QPOS2) {
                float2 v[GS];
#pragma unroll
                for (int j = 0; j < GS; ++j) v[j] = t2[j * QPOS2 + p];
                float2 o0 = make_float2(-cb0, -cb0);
                float2 o1 = make_float2(-cb1, -cb1);
                float2 o2 = make_float2(-cb2, -cb2);
                float2 o3 = make_float2(-cb3, -cb3);
#pragma unroll
                for (int j = 0; j <= R0; ++j) { o0.x = fmaf(w0[j], v[j].x, o0.x); o0.y = fmaf(w0[j], v[j].y, o0.y); }
#pragma unroll
                for (int j = 0; j <= R1; ++j) { o1.x = fmaf(w1[j], v[j].x, o1.x); o1.y = fmaf(w1[j], v[j].y, o1.y); }
#pragma unroll
                for (int j = 0; j <= R2; ++j) { o2.x = fmaf(w2[j], v[j].x, o2.x); o2.y = fmaf(w2[j], v[j].y, o2.y); }
#pragma unroll
                for (int j = 0; j <= R3; ++j) { o3.x = fmaf(w3[j], v[j].x, o3.x); o3.y = fmaf(w3[j], v[j].y, o3.y); }
                const size_t po = (size_t)q * QPOS2 + p;
                obase2[(size_t)R0 * HW2 + po] = o0;
                obase2[(size_t)R1 * HW2 + po] = o1;
                obase2[(size_t)R2 * HW2 + po] = o2;
                obase2[(size_t)R3 * HW2 + po] = o3;
            }
        }
        __builtin_amdgcn_s_barrier();  // all waves done reading tile
        __builtin_amdgcn_sched_barrier(0);
    }
}

__global__ __launch_bounds__(256, 2) void whiten_apply(const float4* __restrict__ x4,
                                                       const float* __restrict__ wmat,
                                                       const float* __restrict__ muv,
                                                       float* __restrict__ out) {
    __shared__ float4 tile4[TILE4];  // 50176 B
    const int tid = threadIdx.x, w = tid >> 6, lane = tid & 63;
    const int g = blockIdx.y;
    const size_t roff = ((size_t)blockIdx.x * D_FEAT + (size_t)g * GS);
    const float4* rbase4 = x4 + roff * HW4;
    float2* obase2 = (float2*)out + roff * HW2;
    switch (w) {
        case 0: apply_wave<0, 15, 4, 11>(rbase4, obase2, wmat, muv, tile4, g, lane); break;
        case 1: apply_wave<1, 14, 5, 10>(rbase4, obase2, wmat, muv, tile4, g, lane); break;
        case 2: apply_wave<2, 13, 6, 9>(rbase4, obase2, wmat, muv, tile4, g, lane); break;
        default: apply_wave<3, 12, 7, 8>(rbase4, obase2, wmat, muv, tile4, g, lane); break;
    }
}

extern "C" void kernel_launch(void* const* d_in, const int* in_sizes, int n_in,
                              void* d_out, int out_size, void* d_ws, size_t ws_size,
                              hipStream_t stream) {
    const float* x = (const float*)d_in[0];
    float* out = (float*)d_out;

    float* ws = (float*)d_ws;
    float* sums = ws;                   // 256 floats
    float* gram = ws + 256;             // 2176 floats
    float* wmat = ws + 256 + 2176;      // 2176 floats
    float* muv  = wmat + 2176;          // 256 floats

    // accumulators must start at zero (ws is poisoned each call)
    hipMemsetAsync(ws, 0, (256 + 2176) * sizeof(float), stream);

    dim3 grid(M_BATCH, NGROUPS);
    whiten_stats<<<grid, 256, 0, stream>>>((const float4*)x, sums, gram);
    whiten_solve<<<1, 64, 0, stream>>>(sums, gram, wmat, muv);
    whiten_apply<<<grid, 256, 0, stream>>>((const float4*)x, wmat, muv, out);
}